// Round 1
// baseline (13280.264 us; speedup 1.0000x reference)
//
#include <hip/hip_runtime.h>
#include <hip/hip_bf16.h>

// DeepSeek-V2 MLA prefill, B=2 S=2048 HID=2048 H=16 DN=128 DR=64 KVR=512 DV=128
// Round 0: correct fp32/bf16-vector baseline (no MFMA). Workspace: 174,063,616 B.

typedef __hip_bfloat16 bf16;

#define S_    2048
#define SCALE_F 0.07216878364870322f   // (128+64)^-0.5

__device__ __forceinline__ float bl(unsigned u){ return __uint_as_float(u<<16); }
__device__ __forceinline__ float bh(unsigned u){ return __uint_as_float(u & 0xffff0000u); }
__device__ __forceinline__ void b8(uint4 v, float* f){
  f[0]=bl(v.x); f[1]=bh(v.x); f[2]=bl(v.y); f[3]=bh(v.y);
  f[4]=bl(v.z); f[5]=bh(v.z); f[6]=bl(v.w); f[7]=bh(v.w);
}
__device__ __forceinline__ void load4(const float* p, float* o){
  float4 v = *(const float4*)p; o[0]=v.x; o[1]=v.y; o[2]=v.z; o[3]=v.w;
}
__device__ __forceinline__ void load4(const bf16* p, float* o){
  uint2 v = *(const uint2*)p; o[0]=bl(v.x); o[1]=bh(v.x); o[2]=bl(v.y); o[3]=bh(v.y);
}
__device__ __forceinline__ void st1(float* p, float v){ *p = v; }
__device__ __forceinline__ void st1(bf16* p, float v){ *p = __float2bfloat16(v); }
__device__ __forceinline__ unsigned pk2(float a, float b){
  unsigned short ua = __builtin_bit_cast(unsigned short, __float2bfloat16(a));
  unsigned short ub = __builtin_bit_cast(unsigned short, __float2bfloat16(b));
  return (unsigned)ua | ((unsigned)ub << 16);
}

// ---------------- cos/sin table: (S,32) each ----------------
__global__ void cossin_kernel(const int* __restrict__ pos, float* __restrict__ cosT,
                              float* __restrict__ sinT){
  int idx = blockIdx.x*256 + threadIdx.x;       // S*32 = 65536
  int i = idx & 31, s = idx >> 5;
  float t = (float)pos[s];
  float freq = t * powf(10000.0f, -(float)i/32.0f);
  cosT[idx] = cosf(freq);
  sinT[idx] = sinf(freq);
}

// ---------------- generic tiled GEMM: C = A @ W^T (NT) or A @ W (NN) --------
// 128x128 tile, BK=8, 256 threads, 8x8 per thread. M must be multiple of 128.
template<bool NT, typename TA, typename TW, typename TC>
__global__ __launch_bounds__(256) void gemm_kernel(
    const TA* __restrict__ A, int lda, int aDiv, long aS1, long aS2,
    const TW* __restrict__ W, int ldw, int wDiv, long wS1, long wS2,
    TC* __restrict__ C, int ldc, int cDiv, long cS1, long cS2,
    int N, int K, float alpha)
{
  int z = blockIdx.z;
  A += (long)(z/aDiv)*aS1 + (long)(z%aDiv)*aS2;
  W += (long)(z/wDiv)*wS1 + (long)(z%wDiv)*wS2;
  C += (long)(z/cDiv)*cS1 + (long)(z%cDiv)*cS2;
  __shared__ float As[8][128];
  __shared__ float Ws[8][128];
  int tid = threadIdx.x;
  int tx = tid & 15, ty = tid >> 4;
  int row0 = blockIdx.y*128, col0 = blockIdx.x*128;
  float acc[8][8];
  #pragma unroll
  for (int i=0;i<8;i++)
    #pragma unroll
    for (int j=0;j<8;j++) acc[i][j] = 0.f;
  int lr = tid >> 1, lk = (tid & 1)*4;
  for (int k0 = 0; k0 < K; k0 += 8){
    float a4[4], w4[4];
    load4(A + (long)(row0+lr)*lda + k0 + lk, a4);
    if (NT) {
      int wn = col0 + lr;
      if (wn < N) load4(W + (long)wn*ldw + k0 + lk, w4);
      else { w4[0]=0;w4[1]=0;w4[2]=0;w4[3]=0; }
    } else {
      int wk = k0 + (tid>>5);
      int wc = col0 + (tid&31)*4;
      if (wc < N) load4(W + (long)wk*ldw + wc, w4);
      else { w4[0]=0;w4[1]=0;w4[2]=0;w4[3]=0; }
    }
    __syncthreads();
    #pragma unroll
    for (int j=0;j<4;j++) As[lk+j][lr] = a4[j];
    if (NT) {
      #pragma unroll
      for (int j=0;j<4;j++) Ws[lk+j][lr] = w4[j];
    } else {
      *(float4*)&Ws[tid>>5][(tid&31)*4] = *(const float4*)w4;
    }
    __syncthreads();
    #pragma unroll
    for (int kk=0;kk<8;kk++){
      float a0[4],a1[4],w0[4],w1[4];
      *(float4*)a0 = *(const float4*)&As[kk][ty*4];
      *(float4*)a1 = *(const float4*)&As[kk][64+ty*4];
      *(float4*)w0 = *(const float4*)&Ws[kk][tx*4];
      *(float4*)w1 = *(const float4*)&Ws[kk][64+tx*4];
      #pragma unroll
      for (int i=0;i<4;i++)
        #pragma unroll
        for (int j=0;j<4;j++){
          acc[i][j]     = fmaf(a0[i], w0[j], acc[i][j]);
          acc[i][j+4]   = fmaf(a0[i], w1[j], acc[i][j+4]);
          acc[i+4][j]   = fmaf(a1[i], w0[j], acc[i+4][j]);
          acc[i+4][j+4] = fmaf(a1[i], w1[j], acc[i+4][j+4]);
        }
    }
  }
  #pragma unroll
  for (int i=0;i<8;i++){
    long r = row0 + ((i<4) ? (ty*4+i) : (64+ty*4+i-4));
    #pragma unroll
    for (int j=0;j<8;j++){
      int c = col0 + ((j<4) ? (tx*4+j) : (64+tx*4+j-4));
      if (c < N) st1(C + r*(long)ldc + c, acc[i][j]*alpha);
    }
  }
}

// ---------------- RMSNorm(ckv) + RoPE(k_pe) -> K bf16 (B,S,576) -------------
__global__ __launch_bounds__(256) void build_k_kernel(
    const float* __restrict__ ckv_kpe, const float* __restrict__ ln_w,
    const float* __restrict__ cosT, const float* __restrict__ sinT,
    bf16* __restrict__ Kb)
{
  int row = blockIdx.x;            // b*S + s
  int s = row & (S_-1);
  int tid = threadIdx.x;
  const float* src = ckv_kpe + (long)row*576;
  float x0 = src[tid*2], x1 = src[tid*2+1];
  float ss = x0*x0 + x1*x1;
  #pragma unroll
  for (int o=32;o>=1;o>>=1) ss += __shfl_xor(ss, o, 64);
  __shared__ float wss[4];
  int wid = tid>>6, lane = tid&63;
  if (lane==0) wss[wid] = ss;
  __syncthreads();
  float tot = wss[0]+wss[1]+wss[2]+wss[3];
  float rs = rsqrtf(tot*(1.0f/512.0f) + 1e-6f);
  bf16* dst = Kb + (long)row*576;
  dst[tid*2]   = __float2bfloat16(x0*rs*ln_w[tid*2]);
  dst[tid*2+1] = __float2bfloat16(x1*rs*ln_w[tid*2+1]);
  if (tid < 32) {
    float p0 = src[512 + tid*2], p1 = src[512 + tid*2 + 1];
    float c = cosT[s*32+tid], sn = sinT[s*32+tid];
    dst[512+tid] = __float2bfloat16(p0*c - p1*sn);
    dst[544+tid] = __float2bfloat16(p1*c + p0*sn);
  }
}

// ---------------- RoPE(q_pe)*SCALE -> Q cols 512..575 -----------------------
__global__ void rope_q_kernel(const float* __restrict__ qpe,
                              const float* __restrict__ cosT, const float* __restrict__ sinT,
                              bf16* __restrict__ Qb)
{
  int idx = blockIdx.x*256 + threadIdx.x;   // B*H*S*32 = 2097152
  int i = idx & 31;
  int s = (idx >> 5) & (S_-1);
  int z = idx >> 16;                        // b*16+n
  int b = z >> 4, n = z & 15;
  long base = ((long)(b*S_+s))*1024 + n*64 + 2*i;
  float x0 = qpe[base], x1 = qpe[base+1];
  float c = cosT[s*32+i], sn = sinT[s*32+i];
  bf16* dst = Qb + ((long)z*S_ + s)*576;
  dst[512+i] = __float2bfloat16((x0*c - x1*sn)*SCALE_F);
  dst[544+i] = __float2bfloat16((x1*c + x0*sn)*SCALE_F);
}

// ---------------- flash-style causal attention ------------------------------
// Q (B*H, S, 576) bf16 (pre-scaled), K (B, S, 576) bf16, V = K[:, :512]
// out_lat (B*H, S, 512) bf16.  Block: 256 thr, 32 queries, 16-key tiles.
__global__ __launch_bounds__(256) void attn_kernel(
    const bf16* __restrict__ Qg, const bf16* __restrict__ Kg, bf16* __restrict__ Og)
{
  __shared__ bf16 Qs[32][576];
  __shared__ bf16 Ks[16][576];
  int qt = blockIdx.x, z = blockIdx.y;
  int b = z >> 4;
  int tid = threadIdx.x;
  int q0 = qt*32;
  {
    const uint4* src = (const uint4*)(Qg + ((long)z*S_ + q0)*576);
    uint4* dst = (uint4*)&Qs[0][0];
    for (int i=tid; i<2304; i+=256) dst[i] = src[i];
  }
  int qown = tid >> 3, dsub = tid & 7;
  int d0 = dsub*64;
  int sq = q0 + qown;
  int tA = dsub*2, tB = tA+1;
  float m = -1e30f, l = 0.f;
  float acc[64];
  #pragma unroll
  for (int i=0;i<64;i++) acc[i] = 0.f;

  for (int kt0 = 0; kt0 < q0+32; kt0 += 16){
    __syncthreads();
    {
      const uint4* src = (const uint4*)(Kg + ((long)b*S_ + kt0)*576);
      uint4* dst = (uint4*)&Ks[0][0];
      for (int i=tid; i<1152; i+=256) dst[i] = src[i];
    }
    __syncthreads();
    float s0 = 0.f, s1 = 0.f;
    const uint4* qr  = (const uint4*)&Qs[qown][0];
    const uint4* k0r = (const uint4*)&Ks[tA][0];
    const uint4* k1r = (const uint4*)&Ks[tB][0];
    #pragma unroll 8
    for (int i=0;i<72;i++){
      float qf[8], kf0[8], kf1[8];
      b8(qr[i],qf); b8(k0r[i],kf0); b8(k1r[i],kf1);
      #pragma unroll
      for (int j=0;j<8;j++){ s0 = fmaf(qf[j],kf0[j],s0); s1 = fmaf(qf[j],kf1[j],s1); }
    }
    if (kt0 + tA > sq) s0 = -1e30f;
    if (kt0 + tB > sq) s1 = -1e30f;
    float pm = fmaxf(s0, s1);
    #pragma unroll
    for (int o=1;o<8;o<<=1) pm = fmaxf(pm, __shfl_xor(pm, o, 8));
    float mn = fmaxf(m, pm);            // first tile always has a valid key (t=0)
    float al = __expf(m - mn);
    float p0 = __expf(s0 - mn), p1 = __expf(s1 - mn);
    float ls = p0 + p1;
    #pragma unroll
    for (int o=1;o<8;o<<=1) ls += __shfl_xor(ls, o, 8);
    l = l*al + ls;
    m = mn;
    #pragma unroll
    for (int i=0;i<64;i++) acc[i] *= al;
    #pragma unroll 2
    for (int th=0; th<8; th++){
      float pa = __shfl(p0, th, 8);
      float pb = __shfl(p1, th, 8);
      const uint4* va = (const uint4*)&Ks[2*th][d0];
      const uint4* vb = (const uint4*)&Ks[2*th+1][d0];
      #pragma unroll
      for (int i=0;i<8;i++){
        float vf[8], wf[8];
        b8(va[i],vf); b8(vb[i],wf);
        #pragma unroll
        for (int j=0;j<8;j++){
          acc[i*8+j] = fmaf(pa, vf[j], acc[i*8+j]);
          acc[i*8+j] = fmaf(pb, wf[j], acc[i*8+j]);
        }
      }
    }
  }
  float inv = 1.f / l;
  bf16* dst = Og + ((long)z*S_ + sq)*512 + d0;
  #pragma unroll
  for (int i=0;i<64;i+=8){
    uint4 o;
    o.x = pk2(acc[i  ]*inv, acc[i+1]*inv);
    o.y = pk2(acc[i+2]*inv, acc[i+3]*inv);
    o.z = pk2(acc[i+4]*inv, acc[i+5]*inv);
    o.w = pk2(acc[i+6]*inv, acc[i+7]*inv);
    *(uint4*)(dst + i) = o;
  }
}

// ---------------- launch ----------------------------------------------------
extern "C" void kernel_launch(void* const* d_in, const int* in_sizes, int n_in,
                              void* d_out, int out_size, void* d_ws, size_t ws_size,
                              hipStream_t stream)
{
  const float* hidden = (const float*)d_in[0];
  const float* qn_w   = (const float*)d_in[1];
  const float* qpe_w  = (const float*)d_in[2];
  const float* kva_w  = (const float*)d_in[3];
  const float* ln_w   = (const float*)d_in[4];
  const float* kb_w   = (const float*)d_in[5];
  const float* vb_w   = (const float*)d_in[6];
  const float* o_w    = (const float*)d_in[7];
  const int*   pos    = (const int*)d_in[8];
  float* out = (float*)d_out;
  char* ws = (char*)d_ws;

  float* cosT  = (float*)(ws);                       //   262144
  float* sinT  = (float*)(ws + 262144);              //   262144
  float* ckv   = (float*)(ws + 524288);              //  9437184  (B,S,576) f32
  bf16*  Qb    = (bf16*) (ws + 9961472);             // 75497472  (B*H,S,576) bf16
  bf16*  Kb    = (bf16*) (ws + 85458944);            //  4718592  (B,S,576) bf16
  bf16*  outl  = (bf16*) (ws + 90177536);            // 67108864  (B*H,S,512) bf16
  float* qnope = (float*)(ws + 90177536);            // 33554432  aliased in outl (dead before attn)
  float* qpe   = (float*)(ws + 123731968);           // 16777216  aliased in outl
  bf16*  voutb = (bf16*) (ws + 157286400);           // 16777216  (B,S,2048) bf16

  cossin_kernel<<<256, 256, 0, stream>>>(pos, cosT, sinT);

  // ckv_kpe = hidden @ kv_a^T   (4096 x 576)
  gemm_kernel<true,float,float,float><<<dim3(5,32,1),256,0,stream>>>(
      hidden,2048, 1,0,0,  kva_w,2048, 1,0,0,  ckv,576, 1,0,0,  576,2048, 1.f);
  // q_nope = hidden @ q_nope_w^T  (4096 x 2048)
  gemm_kernel<true,float,float,float><<<dim3(16,32,1),256,0,stream>>>(
      hidden,2048, 1,0,0,  qn_w,2048, 1,0,0,  qnope,2048, 1,0,0,  2048,2048, 1.f);
  // q_pe_raw = hidden @ q_pe_w^T  (4096 x 1024)
  gemm_kernel<true,float,float,float><<<dim3(8,32,1),256,0,stream>>>(
      hidden,2048, 1,0,0,  qpe_w,2048, 1,0,0,  qpe,1024, 1,0,0,  1024,2048, 1.f);

  build_k_kernel<<<4096, 256, 0, stream>>>(ckv, ln_w, cosT, sinT, Kb);
  rope_q_kernel<<<8192, 256, 0, stream>>>(qpe, cosT, sinT, Qb);

  // q_lat = q_nope @ k_b[n]  (per (b,n): 2048x512, K=128), *SCALE -> Q[:, :512]
  gemm_kernel<false,float,float,bf16><<<dim3(4,16,32),256,0,stream>>>(
      qnope,2048, 16,(long)S_*2048,128,  kb_w,512, 16,0,65536,
      Qb,576, 1,(long)S_*576,0,  512,128, SCALE_F);

  attn_kernel<<<dim3(64,32), 256, 0, stream>>>(Qb, Kb, outl);

  // v_out = out_lat @ v_b[n]^T  (per (b,n): 2048x128, K=512) -> (B,S,H*DV)
  gemm_kernel<true,bf16,float,bf16><<<dim3(1,16,32),256,0,stream>>>(
      outl,512, 1,(long)S_*512,0,  vb_w,512, 16,0,65536,
      voutb,2048, 16,(long)S_*2048,128,  128,512, 1.f);

  // out = v_out @ o_w^T  (4096 x 2048)
  gemm_kernel<true,bf16,float,float><<<dim3(16,32,1),256,0,stream>>>(
      voutb,2048, 1,0,0,  o_w,2048, 1,0,0,  out,2048, 1,0,0,  2048,2048, 1.f);
}

// Round 2
// 3995.002 us; speedup vs baseline: 3.3242x; 3.3242x over previous
//
#include <hip/hip_runtime.h>
#include <hip/hip_bf16.h>

// DeepSeek-V2 MLA prefill, B=2 S=2048 HID=2048 H=16 DN=128 DR=64 KVR=512 DV=128
// Round 1: MFMA flash attention (bf16 16x16x32), fp32 GEMMs unchanged.

typedef __hip_bfloat16 bf16;
typedef __bf16 v8bf __attribute__((ext_vector_type(8)));
typedef float  v4f  __attribute__((ext_vector_type(4)));

#define S_    2048
#define SCALE_F 0.07216878364870322f   // (128+64)^-0.5

__device__ __forceinline__ float bl(unsigned u){ return __uint_as_float(u<<16); }
__device__ __forceinline__ float bh(unsigned u){ return __uint_as_float(u & 0xffff0000u); }
__device__ __forceinline__ void load4(const float* p, float* o){
  float4 v = *(const float4*)p; o[0]=v.x; o[1]=v.y; o[2]=v.z; o[3]=v.w;
}
__device__ __forceinline__ void load4(const bf16* p, float* o){
  uint2 v = *(const uint2*)p; o[0]=bl(v.x); o[1]=bh(v.x); o[2]=bl(v.y); o[3]=bh(v.y);
}
__device__ __forceinline__ void st1(float* p, float v){ *p = v; }
__device__ __forceinline__ void st1(bf16* p, float v){ *p = __float2bfloat16(v); }
__device__ __forceinline__ unsigned short bfb(float x){
  return __builtin_bit_cast(unsigned short, __float2bfloat16(x));
}
__device__ __forceinline__ unsigned hv(const uint4& v, int i){
  unsigned w = (i<2)?v.x:(i<4)?v.y:(i<6)?v.z:v.w;
  return (i&1)? (w>>16) : (w & 0xffffu);
}

// ---------------- cos/sin table: (S,32) each ----------------
__global__ void cossin_kernel(const int* __restrict__ pos, float* __restrict__ cosT,
                              float* __restrict__ sinT){
  int idx = blockIdx.x*256 + threadIdx.x;       // S*32 = 65536
  int i = idx & 31, s = idx >> 5;
  float t = (float)pos[s];
  float freq = t * powf(10000.0f, -(float)i/32.0f);
  cosT[idx] = cosf(freq);
  sinT[idx] = sinf(freq);
}

// ---------------- generic tiled GEMM: C = A @ W^T (NT) or A @ W (NN) --------
template<bool NT, typename TA, typename TW, typename TC>
__global__ __launch_bounds__(256) void gemm_kernel(
    const TA* __restrict__ A, int lda, int aDiv, long aS1, long aS2,
    const TW* __restrict__ W, int ldw, int wDiv, long wS1, long wS2,
    TC* __restrict__ C, int ldc, int cDiv, long cS1, long cS2,
    int N, int K, float alpha)
{
  int z = blockIdx.z;
  A += (long)(z/aDiv)*aS1 + (long)(z%aDiv)*aS2;
  W += (long)(z/wDiv)*wS1 + (long)(z%wDiv)*wS2;
  C += (long)(z/cDiv)*cS1 + (long)(z%cDiv)*cS2;
  __shared__ float As[8][128];
  __shared__ float Ws[8][128];
  int tid = threadIdx.x;
  int tx = tid & 15, ty = tid >> 4;
  int row0 = blockIdx.y*128, col0 = blockIdx.x*128;
  float acc[8][8];
  #pragma unroll
  for (int i=0;i<8;i++)
    #pragma unroll
    for (int j=0;j<8;j++) acc[i][j] = 0.f;
  int lr = tid >> 1, lk = (tid & 1)*4;
  for (int k0 = 0; k0 < K; k0 += 8){
    float a4[4], w4[4];
    load4(A + (long)(row0+lr)*lda + k0 + lk, a4);
    if (NT) {
      int wn = col0 + lr;
      if (wn < N) load4(W + (long)wn*ldw + k0 + lk, w4);
      else { w4[0]=0;w4[1]=0;w4[2]=0;w4[3]=0; }
    } else {
      int wk = k0 + (tid>>5);
      int wc = col0 + (tid&31)*4;
      if (wc < N) load4(W + (long)wk*ldw + wc, w4);
      else { w4[0]=0;w4[1]=0;w4[2]=0;w4[3]=0; }
    }
    __syncthreads();
    #pragma unroll
    for (int j=0;j<4;j++) As[lk+j][lr] = a4[j];
    if (NT) {
      #pragma unroll
      for (int j=0;j<4;j++) Ws[lk+j][lr] = w4[j];
    } else {
      *(float4*)&Ws[tid>>5][(tid&31)*4] = *(const float4*)w4;
    }
    __syncthreads();
    #pragma unroll
    for (int kk=0;kk<8;kk++){
      float a0[4],a1[4],w0[4],w1[4];
      *(float4*)a0 = *(const float4*)&As[kk][ty*4];
      *(float4*)a1 = *(const float4*)&As[kk][64+ty*4];
      *(float4*)w0 = *(const float4*)&Ws[kk][tx*4];
      *(float4*)w1 = *(const float4*)&Ws[kk][64+tx*4];
      #pragma unroll
      for (int i=0;i<4;i++)
        #pragma unroll
        for (int j=0;j<4;j++){
          acc[i][j]     = fmaf(a0[i], w0[j], acc[i][j]);
          acc[i][j+4]   = fmaf(a0[i], w1[j], acc[i][j+4]);
          acc[i+4][j]   = fmaf(a1[i], w0[j], acc[i+4][j]);
          acc[i+4][j+4] = fmaf(a1[i], w1[j], acc[i+4][j+4]);
        }
    }
  }
  #pragma unroll
  for (int i=0;i<8;i++){
    long r = row0 + ((i<4) ? (ty*4+i) : (64+ty*4+i-4));
    #pragma unroll
    for (int j=0;j<8;j++){
      int c = col0 + ((j<4) ? (tx*4+j) : (64+tx*4+j-4));
      if (c < N) st1(C + r*(long)ldc + c, acc[i][j]*alpha);
    }
  }
}

// ---------------- RMSNorm(ckv) + RoPE(k_pe) -> K bf16 (B,S,576) -------------
__global__ __launch_bounds__(256) void build_k_kernel(
    const float* __restrict__ ckv_kpe, const float* __restrict__ ln_w,
    const float* __restrict__ cosT, const float* __restrict__ sinT,
    bf16* __restrict__ Kb)
{
  int row = blockIdx.x;            // b*S + s
  int s = row & (S_-1);
  int tid = threadIdx.x;
  const float* src = ckv_kpe + (long)row*576;
  float x0 = src[tid*2], x1 = src[tid*2+1];
  float ss = x0*x0 + x1*x1;
  #pragma unroll
  for (int o=32;o>=1;o>>=1) ss += __shfl_xor(ss, o, 64);
  __shared__ float wss[4];
  int wid = tid>>6, lane = tid&63;
  if (lane==0) wss[wid] = ss;
  __syncthreads();
  float tot = wss[0]+wss[1]+wss[2]+wss[3];
  float rs = rsqrtf(tot*(1.0f/512.0f) + 1e-6f);
  bf16* dst = Kb + (long)row*576;
  dst[tid*2]   = __float2bfloat16(x0*rs*ln_w[tid*2]);
  dst[tid*2+1] = __float2bfloat16(x1*rs*ln_w[tid*2+1]);
  if (tid < 32) {
    float p0 = src[512 + tid*2], p1 = src[512 + tid*2 + 1];
    float c = cosT[s*32+tid], sn = sinT[s*32+tid];
    dst[512+tid] = __float2bfloat16(p0*c - p1*sn);
    dst[544+tid] = __float2bfloat16(p1*c + p0*sn);
  }
}

// ---------------- RoPE(q_pe)*SCALE -> Q cols 512..575 -----------------------
__global__ void rope_q_kernel(const float* __restrict__ qpe,
                              const float* __restrict__ cosT, const float* __restrict__ sinT,
                              bf16* __restrict__ Qb)
{
  int idx = blockIdx.x*256 + threadIdx.x;   // B*H*S*32 = 2097152
  int i = idx & 31;
  int s = (idx >> 5) & (S_-1);
  int z = idx >> 16;                        // b*16+n
  int b = z >> 4, n = z & 15;
  long base = ((long)(b*S_+s))*1024 + n*64 + 2*i;
  float x0 = qpe[base], x1 = qpe[base+1];
  float c = cosT[s*32+i], sn = sinT[s*32+i];
  bf16* dst = Qb + ((long)z*S_ + s)*576;
  dst[512+i] = __float2bfloat16((x0*c - x1*sn)*SCALE_F);
  dst[544+i] = __float2bfloat16((x1*c + x0*sn)*SCALE_F);
}

// ---------------- MFMA flash attention --------------------------------------
// Q (B*H, S, 576) bf16 pre-scaled; K (B, S, 576) bf16; V = K[:, :512]
// out (B*H, S, 512) bf16. Block: 512 thr (8 waves), QBLK=64, KVBLK=64.
// LDS: Krm[64][1152B] swz | Vt[512][128B] swz | P[64][128B] swz | xc[8][16] f32
#define KRM_OFF 0
#define VT_OFF  73728
#define P_OFF   139264
#define XC_OFF  147456
#define SMEM_BYTES 147968

__global__ __launch_bounds__(512, 2) void attn_mfma_kernel(
    const bf16* __restrict__ Qg, const bf16* __restrict__ Kg, bf16* __restrict__ Og)
{
  extern __shared__ char smem[];
  char* Krm = smem + KRM_OFF;
  char* Vt  = smem + VT_OFF;
  char* Pl  = smem + P_OFF;
  float* xc = (float*)(smem + XC_OFF);   // [8][16]

  const int tid = threadIdx.x;
  const int w   = tid >> 6;
  const int l   = tid & 63;
  const int g   = l >> 4;
  const int c16 = l & 15;
  const int R   = (w & 3) * 16;     // S/O row block within Q tile
  const int C   = (w >> 2) * 32;    // S col half
  const int Dh  = (w >> 2) * 256;   // O d half

  const int qt = blockIdx.x;        // 0..31
  const int z  = blockIdx.y;        // b*16+n
  const int b  = z >> 4;
  const int q0 = qt * 64;

  // Q fragments in registers: rows q0+R+c16, d = kk*32 + g*8 + 0..7
  v8bf qf[18];
  {
    const char* qgb = (const char*)Qg + (((long)z*S_ + q0 + R + c16)*576 + g*8)*2;
    #pragma unroll
    for (int kk=0;kk<18;kk++) qf[kk] = *(const v8bf*)(qgb + kk*64);
  }

  v4f acc[16];
  #pragma unroll
  for (int i=0;i<16;i++) acc[i] = (v4f){0.f,0.f,0.f,0.f};
  float m[4]  = {-1e30f,-1e30f,-1e30f,-1e30f};
  float lsum[4] = {0.f,0.f,0.f,0.f};

  // Vt staging assignment
  const int ko = tid & 7;           // k octet
  const int dc = tid >> 3;          // 0..63, d chunk of 8
  const char* kgb0 = (const char*)Kg + ((long)b*S_)*1152;

  const int ntile = qt + 1;
  for (int t = 0; t < ntile; ++t){
    const int kt0 = t * 64;
    const char* kgb = kgb0 + (long)kt0*1152;
    __syncthreads();   // previous tile's LDS reads done
    // ---- stage Krm (row-major, swizzled) ----
    #pragma unroll
    for (int it=0; it<9; it++){
      int c = it*512 + tid;          // 0..4607 16B chunks
      int r = c / 72;
      int wb = (c - r*72)*16;
      uint4 v = *(const uint4*)(kgb + r*1152 + (wb ^ ((r&7)<<4)));
      *(uint4*)(Krm + c*16) = v;
    }
    // ---- stage Vt (transposed V, swizzled) ----
    {
      uint4 rr[8];
      #pragma unroll
      for (int j=0;j<8;j++)
        rr[j] = *(const uint4*)(kgb + (ko*8+j)*1152 + dc*16);
      #pragma unroll
      for (int i=0;i<8;i++){
        uint4 o;
        o.x = hv(rr[0],i) | (hv(rr[1],i)<<16);
        o.y = hv(rr[2],i) | (hv(rr[3],i)<<16);
        o.z = hv(rr[4],i) | (hv(rr[5],i)<<16);
        o.w = hv(rr[6],i) | (hv(rr[7],i)<<16);
        int d = dc*8 + i;
        *(uint4*)(Vt + ((d*128 + ko*16) ^ ((d&7)<<4))) = o;
      }
    }
    __syncthreads();

    // ---- QK^T: S[16 rows R][32 cols C] per wave ----
    v4f sfr[2];
    sfr[0] = (v4f){0.f,0.f,0.f,0.f};
    sfr[1] = (v4f){0.f,0.f,0.f,0.f};
    #pragma unroll
    for (int kk=0;kk<18;kk++){
      #pragma unroll
      for (int cb=0;cb<2;cb++){
        int kcol = C + cb*16 + c16;
        v8bf kf = *(const v8bf*)(Krm + ((kcol*1152 + kk*64 + g*16) ^ ((kcol&7)<<4)));
        sfr[cb] = __builtin_amdgcn_mfma_f32_16x16x32_bf16(qf[kk], kf, sfr[cb], 0,0,0);
      }
    }
    // ---- causal mask (diagonal tile only) ----
    if (kt0 == q0){
      #pragma unroll
      for (int cb=0;cb<2;cb++)
        #pragma unroll
        for (int r=0;r<4;r++){
          int qrow = R + g*4 + r, kcol = C + cb*16 + c16;
          if (kcol > qrow) sfr[cb][r] = -1e30f;
        }
    }
    // ---- online softmax (cross-wave pair w, w^4 over col halves) ----
    float pm[4];
    #pragma unroll
    for (int r=0;r<4;r++){
      float v = fmaxf(sfr[0][r], sfr[1][r]);
      v = fmaxf(v, __shfl_xor(v, 1)); v = fmaxf(v, __shfl_xor(v, 2));
      v = fmaxf(v, __shfl_xor(v, 4)); v = fmaxf(v, __shfl_xor(v, 8));
      pm[r] = v;
    }
    if (c16 == 0){
      #pragma unroll
      for (int r=0;r<4;r++) xc[w*16 + g*4 + r] = pm[r];
    }
    __syncthreads();
    float al[4], mn[4];
    #pragma unroll
    for (int r=0;r<4;r++){
      float po = xc[(w^4)*16 + g*4 + r];
      mn[r] = fmaxf(m[r], fmaxf(pm[r], po));
      al[r] = __expf(m[r] - mn[r]);
      m[r] = mn[r];
    }
    float ps[4] = {0.f,0.f,0.f,0.f};
    #pragma unroll
    for (int cb=0;cb<2;cb++)
      #pragma unroll
      for (int r=0;r<4;r++){
        float p = __expf(sfr[cb][r] - mn[r]);
        ps[r] += p;
        int row = R + g*4 + r, col = C + cb*16 + c16;
        *(unsigned short*)(Pl + ((row*128 + col*2) ^ ((row&7)<<4))) = bfb(p);
      }
    #pragma unroll
    for (int r=0;r<4;r++){
      float v = ps[r];
      v += __shfl_xor(v, 1); v += __shfl_xor(v, 2);
      v += __shfl_xor(v, 4); v += __shfl_xor(v, 8);
      ps[r] = v;
    }
    __syncthreads();   // partner max reads done; safe to overwrite xc
    if (c16 == 0){
      #pragma unroll
      for (int r=0;r<4;r++) xc[w*16 + g*4 + r] = ps[r];
    }
    __syncthreads();   // sums + P tile visible
    #pragma unroll
    for (int r=0;r<4;r++){
      float pos = xc[(w^4)*16 + g*4 + r];
      lsum[r] = lsum[r]*al[r] + ps[r] + pos;
    }
    // ---- rescale O ----
    #pragma unroll
    for (int cb=0;cb<16;cb++)
      #pragma unroll
      for (int r=0;r<4;r++) acc[cb][r] *= al[r];
    // ---- PV: O[16 rows R][256 cols Dh] ----
    #pragma unroll
    for (int kk=0;kk<2;kk++){
      int arow = R + c16;
      v8bf af = *(const v8bf*)(Pl + ((arow*128 + kk*64 + g*16) ^ ((arow&7)<<4)));
      #pragma unroll
      for (int cb=0;cb<16;cb++){
        int dv = Dh + cb*16 + c16;
        v8bf bfr = *(const v8bf*)(Vt + ((dv*128 + kk*64 + g*16) ^ ((dv&7)<<4)));
        acc[cb] = __builtin_amdgcn_mfma_f32_16x16x32_bf16(af, bfr, acc[cb], 0,0,0);
      }
    }
  }
  // ---- epilogue ----
  float inv[4];
  #pragma unroll
  for (int r=0;r<4;r++) inv[r] = 1.0f / lsum[r];
  #pragma unroll
  for (int cb=0;cb<16;cb++)
    #pragma unroll
    for (int r=0;r<4;r++){
      int qrow = q0 + R + g*4 + r;
      Og[((long)z*S_ + qrow)*512 + Dh + cb*16 + c16] = __float2bfloat16(acc[cb][r]*inv[r]);
    }
}

// ---------------- launch ----------------------------------------------------
extern "C" void kernel_launch(void* const* d_in, const int* in_sizes, int n_in,
                              void* d_out, int out_size, void* d_ws, size_t ws_size,
                              hipStream_t stream)
{
  const float* hidden = (const float*)d_in[0];
  const float* qn_w   = (const float*)d_in[1];
  const float* qpe_w  = (const float*)d_in[2];
  const float* kva_w  = (const float*)d_in[3];
  const float* ln_w   = (const float*)d_in[4];
  const float* kb_w   = (const float*)d_in[5];
  const float* vb_w   = (const float*)d_in[6];
  const float* o_w    = (const float*)d_in[7];
  const int*   pos    = (const int*)d_in[8];
  float* out = (float*)d_out;
  char* ws = (char*)d_ws;

  float* cosT  = (float*)(ws);                       //   262144
  float* sinT  = (float*)(ws + 262144);              //   262144
  float* ckv   = (float*)(ws + 524288);              //  9437184  (B,S,576) f32
  bf16*  Qb    = (bf16*) (ws + 9961472);             // 75497472  (B*H,S,576) bf16
  bf16*  Kb    = (bf16*) (ws + 85458944);            //  4718592  (B,S,576) bf16
  bf16*  outl  = (bf16*) (ws + 90177536);            // 67108864  (B*H,S,512) bf16
  float* qnope = (float*)(ws + 90177536);            // 33554432  aliased in outl (dead before attn)
  float* qpe   = (float*)(ws + 123731968);           // 16777216  aliased in outl
  bf16*  voutb = (bf16*) (ws + 157286400);           // 16777216  (B,S,2048) bf16

  static_assert(sizeof(v8bf) == 16, "v8bf must be 16B");
  hipFuncSetAttribute((const void*)attn_mfma_kernel,
                      hipFuncAttributeMaxDynamicSharedMemorySize, SMEM_BYTES);

  cossin_kernel<<<256, 256, 0, stream>>>(pos, cosT, sinT);

  // ckv_kpe = hidden @ kv_a^T   (4096 x 576)
  gemm_kernel<true,float,float,float><<<dim3(5,32,1),256,0,stream>>>(
      hidden,2048, 1,0,0,  kva_w,2048, 1,0,0,  ckv,576, 1,0,0,  576,2048, 1.f);
  // q_nope = hidden @ q_nope_w^T  (4096 x 2048)
  gemm_kernel<true,float,float,float><<<dim3(16,32,1),256,0,stream>>>(
      hidden,2048, 1,0,0,  qn_w,2048, 1,0,0,  qnope,2048, 1,0,0,  2048,2048, 1.f);
  // q_pe_raw = hidden @ q_pe_w^T  (4096 x 1024)
  gemm_kernel<true,float,float,float><<<dim3(8,32,1),256,0,stream>>>(
      hidden,2048, 1,0,0,  qpe_w,2048, 1,0,0,  qpe,1024, 1,0,0,  1024,2048, 1.f);

  build_k_kernel<<<4096, 256, 0, stream>>>(ckv, ln_w, cosT, sinT, Kb);
  rope_q_kernel<<<8192, 256, 0, stream>>>(qpe, cosT, sinT, Qb);

  // q_lat = q_nope @ k_b[n]  (per (b,n): 2048x512, K=128), *SCALE -> Q[:, :512]
  gemm_kernel<false,float,float,bf16><<<dim3(4,16,32),256,0,stream>>>(
      qnope,2048, 16,(long)S_*2048,128,  kb_w,512, 16,0,65536,
      Qb,576, 1,(long)S_*576,0,  512,128, SCALE_F);

  attn_mfma_kernel<<<dim3(32,32), 512, SMEM_BYTES, stream>>>(Qb, Kb, outl);

  // v_out = out_lat @ v_b[n]^T  (per (b,n): 2048x128, K=512) -> (B,S,H*DV)
  gemm_kernel<true,bf16,float,bf16><<<dim3(1,16,32),256,0,stream>>>(
      outl,512, 1,(long)S_*512,0,  vb_w,512, 16,0,65536,
      voutb,2048, 16,(long)S_*2048,128,  128,512, 1.f);

  // out = v_out @ o_w^T  (4096 x 2048)
  gemm_kernel<true,bf16,float,float><<<dim3(16,32,1),256,0,stream>>>(
      voutb,2048, 1,0,0,  o_w,2048, 1,0,0,  out,2048, 1,0,0,  2048,2048, 1.f);
}

// Round 3
// 2020.566 us; speedup vs baseline: 6.5725x; 1.9772x over previous
//
#include <hip/hip_runtime.h>
#include <hip/hip_bf16.h>

// DeepSeek-V2 MLA prefill, B=2 S=2048 HID=2048 H=16 DN=128 DR=64 KVR=512 DV=128
// Round 3: MFMA everywhere. Attn spill-fix + balanced q-tile pairs; all GEMMs
// bf16 MFMA 128x128x32 with fused f32->bf16 staging. WS total 169.3 MB.

typedef __hip_bfloat16 bf16;
typedef __bf16 v8bf __attribute__((ext_vector_type(8)));
typedef float  v4f  __attribute__((ext_vector_type(4)));

#define S_    2048
#define SCALE_F 0.07216878364870322f   // (128+64)^-0.5

__device__ __forceinline__ float bl(unsigned u){ return __uint_as_float(u<<16); }
__device__ __forceinline__ float bh(unsigned u){ return __uint_as_float(u & 0xffff0000u); }
__device__ __forceinline__ void st1(float* p, float v){ *p = v; }
__device__ __forceinline__ void st1(bf16* p, float v){ *p = __float2bfloat16(v); }
__device__ __forceinline__ unsigned short bfb(float x){
  return __builtin_bit_cast(unsigned short, __float2bfloat16(x));
}
__device__ __forceinline__ unsigned pk2(float a, float b){
  return (unsigned)bfb(a) | ((unsigned)bfb(b) << 16);
}
__device__ __forceinline__ unsigned hv(const uint4& v, int i){
  unsigned w = (i<2)?v.x:(i<4)?v.y:(i<6)?v.z:v.w;
  return (i&1)? (w>>16) : (w & 0xffffu);
}

// raw global loads (8 bf16-equivalent elements), converted at LDS-write time
struct RawF { float4 a, b; };
__device__ __forceinline__ uint4 ldraw(const bf16* p){ return *(const uint4*)p; }
__device__ __forceinline__ RawF  ldraw(const float* p){
  RawF r; r.a = *(const float4*)p; r.b = *(const float4*)(p+4); return r;
}
__device__ __forceinline__ uint4 toBF(uint4 v){ return v; }
__device__ __forceinline__ uint4 toBF(RawF v){
  uint4 r; r.x = pk2(v.a.x,v.a.y); r.y = pk2(v.a.z,v.a.w);
  r.z = pk2(v.b.x,v.b.y); r.w = pk2(v.b.z,v.b.w); return r;
}

// ---------------- cos/sin table: (S,32) each ----------------
__global__ void cossin_kernel(const int* __restrict__ pos, float* __restrict__ cosT,
                              float* __restrict__ sinT){
  int idx = blockIdx.x*256 + threadIdx.x;       // S*32 = 65536
  int i = idx & 31, s = idx >> 5;
  float t = (float)pos[s];
  float freq = t * powf(10000.0f, -(float)i/32.0f);
  cosT[idx] = cosf(freq);
  sinT[idx] = sinf(freq);
}

// ---------------- MFMA GEMM: C = A @ W^T, 128x128 tile, BK=32 ---------------
// 256 thr = 4 waves (2x2), each wave 64x64. A:(M,K) W:(N,K) row-major.
// TA/TW float sources are cast to bf16 during LDS staging.
template<typename TA, typename TW, typename TC>
__global__ __launch_bounds__(256) void gemm_mfma_kernel(
    const TA* __restrict__ A, int lda, int aDiv, long aS1, long aS2,
    const TW* __restrict__ W, int ldw, int wDiv, long wS1, long wS2,
    TC* __restrict__ C, int ldc, int cDiv, long cS1, long cS2,
    int N, int K, float alpha)
{
  int z = blockIdx.z;
  A += (long)(z/aDiv)*aS1 + (long)(z%aDiv)*aS2;
  W += (long)(z/wDiv)*wS1 + (long)(z%wDiv)*wS2;
  C += (long)(z/cDiv)*cS1 + (long)(z%cDiv)*cS2;
  __shared__ bf16 As[128*32];
  __shared__ bf16 Ws[128*32];
  const int tid = threadIdx.x;
  const int w = tid>>6, l = tid&63, g = l>>4, c16 = l&15;
  const int wr = (w>>1)*64, wc = (w&1)*64;
  const int row0 = blockIdx.y*128, col0 = blockIdx.x*128;

  // staging chunks: c in {tid, 256+tid}; row = c>>2, elem-off = (c&3)*8
  const int ca = tid, cb = 256 + tid;
  const long arA = (long)(row0 + (ca>>2))*lda + (ca&3)*8;
  const long arB = (long)(row0 + (cb>>2))*lda + (cb&3)*8;
  int wra = col0 + (ca>>2); if (wra > N-1) wra = N-1;
  int wrb = col0 + (cb>>2); if (wrb > N-1) wrb = N-1;
  const long wrA = (long)wra*ldw + (ca&3)*8;
  const long wrB = (long)wrb*ldw + (cb&3)*8;

  v4f acc[4][4];
  #pragma unroll
  for (int i=0;i<4;i++)
    #pragma unroll
    for (int j=0;j<4;j++) acc[i][j] = (v4f){0.f,0.f,0.f,0.f};

  auto a0 = ldraw(A + arA); auto a1 = ldraw(A + arB);
  auto w0 = ldraw(W + wrA); auto w1 = ldraw(W + wrB);

  for (int k0 = 0; k0 < K; k0 += 32){
    __syncthreads();   // prior LDS reads done
    *(uint4*)(As + ca*8) = toBF(a0);
    *(uint4*)(As + cb*8) = toBF(a1);
    *(uint4*)(Ws + ca*8) = toBF(w0);
    *(uint4*)(Ws + cb*8) = toBF(w1);
    __syncthreads();
    int kn = k0 + 32;
    if (kn < K){
      a0 = ldraw(A + arA + kn); a1 = ldraw(A + arB + kn);
      w0 = ldraw(W + wrA + kn); w1 = ldraw(W + wrB + kn);
    }
    v8bf af[4], bf_[4];
    #pragma unroll
    for (int mi=0;mi<4;mi++) af[mi]  = *(const v8bf*)(As + (wr+mi*16+c16)*32 + g*8);
    #pragma unroll
    for (int ni=0;ni<4;ni++) bf_[ni] = *(const v8bf*)(Ws + (wc+ni*16+c16)*32 + g*8);
    #pragma unroll
    for (int mi=0;mi<4;mi++)
      #pragma unroll
      for (int ni=0;ni<4;ni++)
        acc[mi][ni] = __builtin_amdgcn_mfma_f32_16x16x32_bf16(af[mi], bf_[ni], acc[mi][ni], 0,0,0);
  }
  #pragma unroll
  for (int mi=0;mi<4;mi++)
    #pragma unroll
    for (int ni=0;ni<4;ni++)
      #pragma unroll
      for (int r=0;r<4;r++){
        int row = row0 + wr + mi*16 + g*4 + r;
        int col = col0 + wc + ni*16 + c16;
        if (col < N) st1(C + (long)row*ldc + col, acc[mi][ni][r]*alpha);
      }
}

// ---------------- k_b cast+transpose: (16,128,512)f32 -> (16,512,128)bf16 ----
__global__ __launch_bounds__(256) void kbT_kernel(const float* __restrict__ kb,
                                                  bf16* __restrict__ kbT){
  __shared__ bf16 t[64][65];
  int h = blockIdx.z, c0 = blockIdx.x*64, d0 = blockIdx.y*64;
  const float* src = kb + ((long)h*128 + d0)*512 + c0;
  #pragma unroll
  for (int i=0;i<16;i++){
    int idx = i*256 + threadIdx.x;
    int dl = idx>>6, cl = idx&63;
    t[dl][cl] = __float2bfloat16(src[(long)dl*512 + cl]);
  }
  __syncthreads();
  bf16* dst = kbT + ((long)h*512 + c0)*128 + d0;
  #pragma unroll
  for (int i=0;i<16;i++){
    int idx = i*256 + threadIdx.x;
    int cl = idx>>6, dl = idx&63;
    dst[(long)cl*128 + dl] = t[dl][cl];
  }
}

// ---------------- RMSNorm(ckv) + RoPE(k_pe) -> K bf16 (B,S,576) -------------
__global__ __launch_bounds__(256) void build_k_kernel(
    const bf16* __restrict__ ckv_kpe, const float* __restrict__ ln_w,
    const float* __restrict__ cosT, const float* __restrict__ sinT,
    bf16* __restrict__ Kb)
{
  int row = blockIdx.x;            // b*S + s
  int s = row & (S_-1);
  int tid = threadIdx.x;
  const bf16* src = ckv_kpe + (long)row*576;
  float x0 = __bfloat162float(src[tid*2]), x1 = __bfloat162float(src[tid*2+1]);
  float ss = x0*x0 + x1*x1;
  #pragma unroll
  for (int o=32;o>=1;o>>=1) ss += __shfl_xor(ss, o, 64);
  __shared__ float wss[4];
  int wid = tid>>6, lane = tid&63;
  if (lane==0) wss[wid] = ss;
  __syncthreads();
  float tot = wss[0]+wss[1]+wss[2]+wss[3];
  float rs = rsqrtf(tot*(1.0f/512.0f) + 1e-6f);
  bf16* dst = Kb + (long)row*576;
  dst[tid*2]   = __float2bfloat16(x0*rs*ln_w[tid*2]);
  dst[tid*2+1] = __float2bfloat16(x1*rs*ln_w[tid*2+1]);
  if (tid < 32) {
    float p0 = __bfloat162float(src[512 + tid*2]);
    float p1 = __bfloat162float(src[512 + tid*2 + 1]);
    float c = cosT[s*32+tid], sn = sinT[s*32+tid];
    dst[512+tid] = __float2bfloat16(p0*c - p1*sn);
    dst[544+tid] = __float2bfloat16(p1*c + p0*sn);
  }
}

// ---------------- RoPE(q_pe)*SCALE -> Q cols 512..575 -----------------------
__global__ void rope_q_kernel(const bf16* __restrict__ qpe,
                              const float* __restrict__ cosT, const float* __restrict__ sinT,
                              bf16* __restrict__ Qb)
{
  int idx = blockIdx.x*256 + threadIdx.x;   // B*H*S*32 = 2097152
  int i = idx & 31;
  int s = (idx >> 5) & (S_-1);
  int z = idx >> 16;                        // b*16+n
  int b = z >> 4, n = z & 15;
  long base = ((long)(b*S_+s))*1024 + n*64 + 2*i;
  float x0 = __bfloat162float(qpe[base]), x1 = __bfloat162float(qpe[base+1]);
  float c = cosT[s*32+i], sn = sinT[s*32+i];
  bf16* dst = Qb + ((long)z*S_ + s)*576;
  dst[512+i] = __float2bfloat16((x0*c - x1*sn)*SCALE_F);
  dst[544+i] = __float2bfloat16((x1*c + x0*sn)*SCALE_F);
}

// ---------------- MFMA flash attention --------------------------------------
// Q (B*H, S, 576) bf16 pre-scaled; K (B, S, 576) bf16; V = K[:, :512]
// out (B*H, S, 512) bf16. Block: 512 thr (8 waves). Block i does q-tiles
// {i, 31-i} (QBLK=64) -> uniform 33 KV tiles per block. KVBLK=64.
#define KRM_OFF 0
#define VT_OFF  73728
#define P_OFF   139264
#define XC_OFF  147456
#define SMEM_BYTES 148480

__global__ __launch_bounds__(512, 1) void attn_mfma_kernel(
    const bf16* __restrict__ Qg, const bf16* __restrict__ Kg, bf16* __restrict__ Og)
{
  extern __shared__ char smem[];
  char* Krm = smem + KRM_OFF;
  char* Vt  = smem + VT_OFF;
  char* Pl  = smem + P_OFF;
  float* xcM = (float*)(smem + XC_OFF);        // [8][16]
  float* xcS = (float*)(smem + XC_OFF + 512);  // [8][16]

  const int tid = threadIdx.x;
  const int w   = tid >> 6;
  const int l   = tid & 63;
  const int g   = l >> 4;
  const int c16 = l & 15;
  const int R   = (w & 3) * 16;     // S/O row block within Q tile
  const int C   = (w >> 2) * 32;    // S col half
  const int Dh  = (w >> 2) * 256;   // O d half

  const int z  = blockIdx.y;        // b*16+n
  const int b  = z >> 4;
  const int ko = tid & 7;           // Vt staging: k octet
  const int dc = tid >> 3;          // Vt staging: d chunk of 8
  const char* kgb0 = (const char*)Kg + ((long)b*S_)*1152;

  for (int ph = 0; ph < 2; ++ph){
    const int qt = ph ? (31 - blockIdx.x) : blockIdx.x;
    const int q0 = qt * 64;

    // Q fragments in registers: rows q0+R+c16, d = kk*32 + g*8 + 0..7
    v8bf qf[18];
    {
      const char* qgb = (const char*)Qg + (((long)z*S_ + q0 + R + c16)*576 + g*8)*2;
      #pragma unroll
      for (int kk=0;kk<18;kk++) qf[kk] = *(const v8bf*)(qgb + kk*64);
    }
    v4f acc[16];
    #pragma unroll
    for (int i=0;i<16;i++) acc[i] = (v4f){0.f,0.f,0.f,0.f};
    float m[4]  = {-1e30f,-1e30f,-1e30f,-1e30f};
    float lsum[4] = {0.f,0.f,0.f,0.f};

    const int ntile = qt + 1;
    for (int t = 0; t < ntile; ++t){
      const int kt0 = t * 64;
      const char* kgb = kgb0 + (long)kt0*1152;
      __syncthreads();   // (1) previous tile/phase LDS reads done
      // ---- stage Krm (row-major, swizzled) ----
      #pragma unroll
      for (int it=0; it<9; it++){
        int c = it*512 + tid;          // 0..4607 16B chunks
        int r = c / 72;
        int wb = (c - r*72)*16;
        uint4 v = *(const uint4*)(kgb + r*1152 + (wb ^ ((r&7)<<4)));
        *(uint4*)(Krm + c*16) = v;
      }
      // ---- stage Vt (transposed V, swizzled) ----
      {
        uint4 rr[8];
        #pragma unroll
        for (int j=0;j<8;j++)
          rr[j] = *(const uint4*)(kgb + (ko*8+j)*1152 + dc*16);
        #pragma unroll
        for (int i=0;i<8;i++){
          uint4 o;
          o.x = hv(rr[0],i) | (hv(rr[1],i)<<16);
          o.y = hv(rr[2],i) | (hv(rr[3],i)<<16);
          o.z = hv(rr[4],i) | (hv(rr[5],i)<<16);
          o.w = hv(rr[6],i) | (hv(rr[7],i)<<16);
          int d = dc*8 + i;
          *(uint4*)(Vt + ((d*128 + ko*16) ^ ((d&7)<<4))) = o;
        }
      }
      __syncthreads();   // (2) tiles staged

      // ---- QK^T: S[16 rows R][32 cols C] per wave ----
      v4f sfr[2];
      sfr[0] = (v4f){0.f,0.f,0.f,0.f};
      sfr[1] = (v4f){0.f,0.f,0.f,0.f};
      #pragma unroll
      for (int kk=0;kk<18;kk++){
        #pragma unroll
        for (int cb=0;cb<2;cb++){
          int kcol = C + cb*16 + c16;
          v8bf kf = *(const v8bf*)(Krm + ((kcol*1152 + kk*64 + g*16) ^ ((kcol&7)<<4)));
          sfr[cb] = __builtin_amdgcn_mfma_f32_16x16x32_bf16(qf[kk], kf, sfr[cb], 0,0,0);
        }
      }
      // ---- causal mask (diagonal tile only) ----
      if (kt0 == q0){
        #pragma unroll
        for (int cb=0;cb<2;cb++)
          #pragma unroll
          for (int r=0;r<4;r++){
            int qrow = R + g*4 + r, kcol = C + cb*16 + c16;
            if (kcol > qrow) sfr[cb][r] = -1e30f;
          }
      }
      // ---- online softmax (cross-wave pair w, w^4 over col halves) ----
      float pm[4];
      #pragma unroll
      for (int r=0;r<4;r++){
        float v = fmaxf(sfr[0][r], sfr[1][r]);
        v = fmaxf(v, __shfl_xor(v, 1)); v = fmaxf(v, __shfl_xor(v, 2));
        v = fmaxf(v, __shfl_xor(v, 4)); v = fmaxf(v, __shfl_xor(v, 8));
        pm[r] = v;
      }
      if (c16 == 0){
        #pragma unroll
        for (int r=0;r<4;r++) xcM[w*16 + g*4 + r] = pm[r];
      }
      __syncthreads();   // (3) partner maxes visible
      float al[4], mn[4];
      #pragma unroll
      for (int r=0;r<4;r++){
        float po = xcM[(w^4)*16 + g*4 + r];
        mn[r] = fmaxf(m[r], fmaxf(pm[r], po));
        al[r] = __expf(m[r] - mn[r]);
        m[r] = mn[r];
      }
      float ps[4] = {0.f,0.f,0.f,0.f};
      #pragma unroll
      for (int cb=0;cb<2;cb++)
        #pragma unroll
        for (int r=0;r<4;r++){
          float p = __expf(sfr[cb][r] - mn[r]);
          ps[r] += p;
          int row = R + g*4 + r, col = C + cb*16 + c16;
          *(unsigned short*)(Pl + ((row*128 + col*2) ^ ((row&7)<<4))) = bfb(p);
        }
      #pragma unroll
      for (int r=0;r<4;r++){
        float v = ps[r];
        v += __shfl_xor(v, 1); v += __shfl_xor(v, 2);
        v += __shfl_xor(v, 4); v += __shfl_xor(v, 8);
        ps[r] = v;
      }
      if (c16 == 0){
        #pragma unroll
        for (int r=0;r<4;r++) xcS[w*16 + g*4 + r] = ps[r];
      }
      __syncthreads();   // (4) P tile + partner sums visible
      #pragma unroll
      for (int r=0;r<4;r++){
        float pos = xcS[(w^4)*16 + g*4 + r];
        lsum[r] = lsum[r]*al[r] + ps[r] + pos;
      }
      // ---- rescale O ----
      #pragma unroll
      for (int cb=0;cb<16;cb++)
        #pragma unroll
        for (int r=0;r<4;r++) acc[cb][r] *= al[r];
      // ---- PV: O[16 rows R][256 cols Dh] ----
      #pragma unroll
      for (int kk=0;kk<2;kk++){
        int arow = R + c16;
        v8bf af = *(const v8bf*)(Pl + ((arow*128 + kk*64 + g*16) ^ ((arow&7)<<4)));
        #pragma unroll
        for (int cb=0;cb<16;cb++){
          int dv = Dh + cb*16 + c16;
          v8bf bfr = *(const v8bf*)(Vt + ((dv*128 + kk*64 + g*16) ^ ((dv&7)<<4)));
          acc[cb] = __builtin_amdgcn_mfma_f32_16x16x32_bf16(af, bfr, acc[cb], 0,0,0);
        }
      }
    }
    // ---- epilogue ----
    float inv[4];
    #pragma unroll
    for (int r=0;r<4;r++) inv[r] = 1.0f / lsum[r];
    #pragma unroll
    for (int cb=0;cb<16;cb++)
      #pragma unroll
      for (int r=0;r<4;r++){
        int qrow = q0 + R + g*4 + r;
        Og[((long)z*S_ + qrow)*512 + Dh + cb*16 + c16] = __float2bfloat16(acc[cb][r]*inv[r]);
      }
  }
}

// ---------------- launch ----------------------------------------------------
extern "C" void kernel_launch(void* const* d_in, const int* in_sizes, int n_in,
                              void* d_out, int out_size, void* d_ws, size_t ws_size,
                              hipStream_t stream)
{
  const float* hidden = (const float*)d_in[0];
  const float* qn_w   = (const float*)d_in[1];
  const float* qpe_w  = (const float*)d_in[2];
  const float* kva_w  = (const float*)d_in[3];
  const float* ln_w   = (const float*)d_in[4];
  const float* kb_w   = (const float*)d_in[5];
  const float* vb_w   = (const float*)d_in[6];
  const float* o_w    = (const float*)d_in[7];
  const int*   pos    = (const int*)d_in[8];
  float* out = (float*)d_out;
  char* ws = (char*)d_ws;

  float* cosT  = (float*)(ws);                 //    262144
  float* sinT  = (float*)(ws + 262144);        //    262144
  bf16*  ckvb  = (bf16*) (ws + 524288);        //  4718592  (B,S,576)
  bf16*  Qb    = (bf16*) (ws + 5242880);       // 75497472  (B*H,S,576)
  bf16*  Kb    = (bf16*) (ws + 80740352);      //  4718592  (B,S,576)
  bf16*  outl  = (bf16*) (ws + 85458944);      // 67108864  (B*H,S,512)
  bf16*  qnopeb= (bf16*) (ws + 85458944);      // 16777216  alias in outl (dead pre-attn)
  bf16*  qpeb  = (bf16*) (ws + 102236160);     //  8388608  alias in outl
  bf16*  kbT   = (bf16*) (ws + 110624768);     //  2097152  alias in outl
  bf16*  voutb = (bf16*) (ws + 152567808);     // 16777216  (B,S,2048)  [ends 169345024]

  static_assert(sizeof(v8bf) == 16, "v8bf must be 16B");
  hipFuncSetAttribute((const void*)attn_mfma_kernel,
                      hipFuncAttributeMaxDynamicSharedMemorySize, SMEM_BYTES);

  cossin_kernel<<<256, 256, 0, stream>>>(pos, cosT, sinT);

  // ckv_kpe = hidden @ kv_a^T   (4096 x 576, K=2048)
  gemm_mfma_kernel<float,float,bf16><<<dim3(5,32,1),256,0,stream>>>(
      hidden,2048, 1,0,0,  kva_w,2048, 1,0,0,  ckvb,576, 1,0,0,  576,2048, 1.f);
  // q_nope = hidden @ q_nope_w^T  (4096 x 2048)
  gemm_mfma_kernel<float,float,bf16><<<dim3(16,32,1),256,0,stream>>>(
      hidden,2048, 1,0,0,  qn_w,2048, 1,0,0,  qnopeb,2048, 1,0,0,  2048,2048, 1.f);
  // q_pe_raw = hidden @ q_pe_w^T  (4096 x 1024)
  gemm_mfma_kernel<float,float,bf16><<<dim3(8,32,1),256,0,stream>>>(
      hidden,2048, 1,0,0,  qpe_w,2048, 1,0,0,  qpeb,1024, 1,0,0,  1024,2048, 1.f);

  kbT_kernel<<<dim3(8,2,16), 256, 0, stream>>>(kb_w, kbT);
  build_k_kernel<<<4096, 256, 0, stream>>>(ckvb, ln_w, cosT, sinT, Kb);
  rope_q_kernel<<<8192, 256, 0, stream>>>(qpeb, cosT, sinT, Qb);

  // q_lat = q_nope @ kbT[n]^T  (per (b,n): 2048x512, K=128), *SCALE -> Q[:, :512]
  gemm_mfma_kernel<bf16,bf16,bf16><<<dim3(4,16,32),256,0,stream>>>(
      qnopeb,2048, 16,(long)S_*2048,128,  kbT,128, 16,0,65536,
      Qb,576, 1,(long)S_*576,0,  512,128, SCALE_F);

  attn_mfma_kernel<<<dim3(16,32), 512, SMEM_BYTES, stream>>>(Qb, Kb, outl);

  // v_out = out_lat @ v_b[n]^T  (per (b,n): 2048x128, K=512) -> (B,S,H*DV)
  gemm_mfma_kernel<bf16,float,bf16><<<dim3(1,16,32),256,0,stream>>>(
      outl,512, 1,(long)S_*512,0,  vb_w,512, 16,0,65536,
      voutb,2048, 16,(long)S_*2048,128,  128,512, 1.f);

  // out = v_out @ o_w^T  (4096 x 2048)
  gemm_mfma_kernel<bf16,float,float><<<dim3(16,32,1),256,0,stream>>>(
      voutb,2048, 1,0,0,  o_w,2048, 1,0,0,  out,2048, 1,0,0,  2048,2048, 1.f);
}

// Round 4
// 756.425 us; speedup vs baseline: 17.5566x; 2.6712x over previous
//
#include <hip/hip_runtime.h>
#include <hip/hip_bf16.h>

// DeepSeek-V2 MLA prefill, B=2 S=2048 HID=2048 H=16 DN=128 DR=64 KVR=512 DV=128
// Round 4: attn rewrite — double-buffered global_load_lds staging (1 barrier/tile),
// wave-private softmax (redundant QK per d-half pair), d-major V copy (Kd).

typedef __hip_bfloat16 bf16;
typedef __bf16 v8bf __attribute__((ext_vector_type(8)));
typedef float  v4f  __attribute__((ext_vector_type(4)));

#define S_    2048
#define SCALE_F 0.07216878364870322f   // (128+64)^-0.5

__device__ __forceinline__ void st1(float* p, float v){ *p = v; }
__device__ __forceinline__ void st1(bf16* p, float v){ *p = __float2bfloat16(v); }
__device__ __forceinline__ unsigned short bfb(float x){
  return __builtin_bit_cast(unsigned short, __float2bfloat16(x));
}
__device__ __forceinline__ unsigned pk2(float a, float b){
  return (unsigned)bfb(a) | ((unsigned)bfb(b) << 16);
}

// async global->LDS 16B (linear LDS dest = wave-uniform base + lane*16)
typedef const void __attribute__((address_space(1)))* gas_t;
typedef void __attribute__((address_space(3)))* las_t;
__device__ __forceinline__ void g2l16(const void* g, void* l){
  __builtin_amdgcn_global_load_lds((gas_t)g, (las_t)l, 16, 0, 0);
}

// raw global loads (8 bf16-equivalent elements), converted at LDS-write time
struct RawF { float4 a, b; };
__device__ __forceinline__ uint4 ldraw(const bf16* p){ return *(const uint4*)p; }
__device__ __forceinline__ RawF  ldraw(const float* p){
  RawF r; r.a = *(const float4*)p; r.b = *(const float4*)(p+4); return r;
}
__device__ __forceinline__ uint4 toBF(uint4 v){ return v; }
__device__ __forceinline__ uint4 toBF(RawF v){
  uint4 r; r.x = pk2(v.a.x,v.a.y); r.y = pk2(v.a.z,v.a.w);
  r.z = pk2(v.b.x,v.b.y); r.w = pk2(v.b.z,v.b.w); return r;
}

// ---------------- cos/sin table: (S,32) each ----------------
__global__ void cossin_kernel(const int* __restrict__ pos, float* __restrict__ cosT,
                              float* __restrict__ sinT){
  int idx = blockIdx.x*256 + threadIdx.x;       // S*32 = 65536
  int i = idx & 31, s = idx >> 5;
  float t = (float)pos[s];
  float freq = t * powf(10000.0f, -(float)i/32.0f);
  cosT[idx] = cosf(freq);
  sinT[idx] = sinf(freq);
}

// ---------------- MFMA GEMM: C = A @ W^T, 128x128 tile, BK=32 ---------------
template<typename TA, typename TW, typename TC>
__global__ __launch_bounds__(256) void gemm_mfma_kernel(
    const TA* __restrict__ A, int lda, int aDiv, long aS1, long aS2,
    const TW* __restrict__ W, int ldw, int wDiv, long wS1, long wS2,
    TC* __restrict__ C, int ldc, int cDiv, long cS1, long cS2,
    int N, int K, float alpha)
{
  int z = blockIdx.z;
  A += (long)(z/aDiv)*aS1 + (long)(z%aDiv)*aS2;
  W += (long)(z/wDiv)*wS1 + (long)(z%wDiv)*wS2;
  C += (long)(z/cDiv)*cS1 + (long)(z%cDiv)*cS2;
  __shared__ bf16 As[128*32];
  __shared__ bf16 Ws[128*32];
  const int tid = threadIdx.x;
  const int w = tid>>6, l = tid&63, g = l>>4, c16 = l&15;
  const int wr = (w>>1)*64, wc = (w&1)*64;
  const int row0 = blockIdx.y*128, col0 = blockIdx.x*128;

  const int ca = tid, cb = 256 + tid;
  const long arA = (long)(row0 + (ca>>2))*lda + (ca&3)*8;
  const long arB = (long)(row0 + (cb>>2))*lda + (cb&3)*8;
  int wra = col0 + (ca>>2); if (wra > N-1) wra = N-1;
  int wrb = col0 + (cb>>2); if (wrb > N-1) wrb = N-1;
  const long wrA = (long)wra*ldw + (ca&3)*8;
  const long wrB = (long)wrb*ldw + (cb&3)*8;

  v4f acc[4][4];
  #pragma unroll
  for (int i=0;i<4;i++)
    #pragma unroll
    for (int j=0;j<4;j++) acc[i][j] = (v4f){0.f,0.f,0.f,0.f};

  auto a0 = ldraw(A + arA); auto a1 = ldraw(A + arB);
  auto w0 = ldraw(W + wrA); auto w1 = ldraw(W + wrB);

  for (int k0 = 0; k0 < K; k0 += 32){
    __syncthreads();
    *(uint4*)(As + ca*8) = toBF(a0);
    *(uint4*)(As + cb*8) = toBF(a1);
    *(uint4*)(Ws + ca*8) = toBF(w0);
    *(uint4*)(Ws + cb*8) = toBF(w1);
    __syncthreads();
    int kn = k0 + 32;
    if (kn < K){
      a0 = ldraw(A + arA + kn); a1 = ldraw(A + arB + kn);
      w0 = ldraw(W + wrA + kn); w1 = ldraw(W + wrB + kn);
    }
    v8bf af[4], bf_[4];
    #pragma unroll
    for (int mi=0;mi<4;mi++) af[mi]  = *(const v8bf*)(As + (wr+mi*16+c16)*32 + g*8);
    #pragma unroll
    for (int ni=0;ni<4;ni++) bf_[ni] = *(const v8bf*)(Ws + (wc+ni*16+c16)*32 + g*8);
    #pragma unroll
    for (int mi=0;mi<4;mi++)
      #pragma unroll
      for (int ni=0;ni<4;ni++)
        acc[mi][ni] = __builtin_amdgcn_mfma_f32_16x16x32_bf16(af[mi], bf_[ni], acc[mi][ni], 0,0,0);
  }
  #pragma unroll
  for (int mi=0;mi<4;mi++)
    #pragma unroll
    for (int ni=0;ni<4;ni++)
      #pragma unroll
      for (int r=0;r<4;r++){
        int row = row0 + wr + mi*16 + g*4 + r;
        int col = col0 + wc + ni*16 + c16;
        if (col < N) st1(C + (long)row*ldc + col, acc[mi][ni][r]*alpha);
      }
}

// ---------------- k_b cast+transpose: (16,128,512)f32 -> (16,512,128)bf16 ----
__global__ __launch_bounds__(256) void kbT_kernel(const float* __restrict__ kb,
                                                  bf16* __restrict__ kbT){
  __shared__ bf16 t[64][65];
  int h = blockIdx.z, c0 = blockIdx.x*64, d0 = blockIdx.y*64;
  const float* src = kb + ((long)h*128 + d0)*512 + c0;
  #pragma unroll
  for (int i=0;i<16;i++){
    int idx = i*256 + threadIdx.x;
    int dl = idx>>6, cl = idx&63;
    t[dl][cl] = __float2bfloat16(src[(long)dl*512 + cl]);
  }
  __syncthreads();
  bf16* dst = kbT + ((long)h*512 + c0)*128 + d0;
  #pragma unroll
  for (int i=0;i<16;i++){
    int idx = i*256 + threadIdx.x;
    int cl = idx>>6, dl = idx&63;
    dst[(long)cl*128 + dl] = t[dl][cl];
  }
}

// ---------------- V transpose: Kb(B,S,576)[:,:512] -> Kd(B,512,S) bf16 ------
__global__ __launch_bounds__(256) void tposeV_kernel(const bf16* __restrict__ Kb,
                                                     bf16* __restrict__ Kd){
  __shared__ bf16 t[64][65];
  int b = blockIdx.z, s0 = blockIdx.y*64, d0 = blockIdx.x*64;
  const bf16* src = Kb + ((long)(b*S_ + s0))*576 + d0;
  #pragma unroll
  for (int i=0;i<16;i++){
    int idx = i*256 + threadIdx.x;
    int sl = idx>>6, dl = idx&63;
    t[sl][dl] = src[(long)sl*576 + dl];
  }
  __syncthreads();
  bf16* dst = Kd + ((long)(b*512 + d0))*S_ + s0;
  #pragma unroll
  for (int i=0;i<16;i++){
    int idx = i*256 + threadIdx.x;
    int dl = idx>>6, sl = idx&63;
    dst[(long)dl*S_ + sl] = t[sl][dl];
  }
}

// ---------------- RMSNorm(ckv) + RoPE(k_pe) -> K bf16 (B,S,576) -------------
__global__ __launch_bounds__(256) void build_k_kernel(
    const bf16* __restrict__ ckv_kpe, const float* __restrict__ ln_w,
    const float* __restrict__ cosT, const float* __restrict__ sinT,
    bf16* __restrict__ Kb)
{
  int row = blockIdx.x;            // b*S + s
  int s = row & (S_-1);
  int tid = threadIdx.x;
  const bf16* src = ckv_kpe + (long)row*576;
  float x0 = __bfloat162float(src[tid*2]), x1 = __bfloat162float(src[tid*2+1]);
  float ss = x0*x0 + x1*x1;
  #pragma unroll
  for (int o=32;o>=1;o>>=1) ss += __shfl_xor(ss, o, 64);
  __shared__ float wss[4];
  int wid = tid>>6, lane = tid&63;
  if (lane==0) wss[wid] = ss;
  __syncthreads();
  float tot = wss[0]+wss[1]+wss[2]+wss[3];
  float rs = rsqrtf(tot*(1.0f/512.0f) + 1e-6f);
  bf16* dst = Kb + (long)row*576;
  dst[tid*2]   = __float2bfloat16(x0*rs*ln_w[tid*2]);
  dst[tid*2+1] = __float2bfloat16(x1*rs*ln_w[tid*2+1]);
  if (tid < 32) {
    float p0 = __bfloat162float(src[512 + tid*2]);
    float p1 = __bfloat162float(src[512 + tid*2 + 1]);
    float c = cosT[s*32+tid], sn = sinT[s*32+tid];
    dst[512+tid] = __float2bfloat16(p0*c - p1*sn);
    dst[544+tid] = __float2bfloat16(p1*c + p0*sn);
  }
}

// ---------------- RoPE(q_pe)*SCALE -> Q cols 512..575 -----------------------
__global__ void rope_q_kernel(const bf16* __restrict__ qpe,
                              const float* __restrict__ cosT, const float* __restrict__ sinT,
                              bf16* __restrict__ Qb)
{
  int idx = blockIdx.x*256 + threadIdx.x;   // B*H*S*32 = 2097152
  int i = idx & 31;
  int s = (idx >> 5) & (S_-1);
  int z = idx >> 16;                        // b*16+n
  int b = z >> 4, n = z & 15;
  long base = ((long)(b*S_+s))*1024 + n*64 + 2*i;
  float x0 = __bfloat162float(qpe[base]), x1 = __bfloat162float(qpe[base+1]);
  float c = cosT[s*32+i], sn = sinT[s*32+i];
  bf16* dst = Qb + ((long)z*S_ + s)*576;
  dst[512+i] = __float2bfloat16((x0*c - x1*sn)*SCALE_F);
  dst[544+i] = __float2bfloat16((x1*c + x0*sn)*SCALE_F);
}

// ---------------- MFMA flash attention (round 4) -----------------------------
// Q (B*H,S,576) bf16 pre-scaled; K (B,S,576) bf16; Kd (B,512,S) bf16 (V^T).
// 512 thr = 8 waves: 4 row-blocks x 2 d-halves. KVBLK=32, QBLK=64.
// Pair waves (w, w^4) duplicate QK + softmax -> no cross-wave exchange.
// Double-buffered K/V staging via global_load_lds; 1 barrier/tile.
#define KBUFB 36864
#define VBUFB 32768
#define K0_OFF 0
#define K1_OFF 36864
#define V0_OFF 73728
#define V1_OFF 106496
#define P_OFF  139264
#define SMEM_BYTES 147456

__global__ __launch_bounds__(512, 2) void attn_mfma_kernel(
    const bf16* __restrict__ Qg, const bf16* __restrict__ Kg,
    const bf16* __restrict__ Vdg, bf16* __restrict__ Og)
{
  extern __shared__ char smem[];
  const int tid = threadIdx.x;
  const int w   = tid >> 6;
  const int l   = tid & 63;
  const int g   = l >> 4;
  const int c16 = l & 15;
  const int R   = (w & 3) * 16;     // row block within Q tile
  const int Dh  = (w >> 2) * 256;   // O d half
  char* Pw = smem + P_OFF + w*1024; // wave-private P: 16 rows x 64B (striped swz)

  // XCD-aware mapping: each XCD works on one batch b
  const int lin = blockIdx.x;       // 0..511
  const int k8 = lin & 7;
  const int b  = k8 >> 2;
  const int u  = (lin >> 3)*4 + (k8 & 3);   // 0..255
  const int n  = u & 15;
  const int pr = u >> 4;                    // 0..15 (q-tile pair id)
  const int z  = b*16 + n;

  const char* kb0 = (const char*)Kg  + (long)b*S_*1152;
  const char* vd0 = (const char*)Vdg + (long)b*512*S_*2;

  // stage one 32-row K tile + V tile into LDS (linear dest, pre-swizzled src)
  auto STAGE = [&](int tt, char* kd, char* vd){
    const char* ksrc = kb0 + (long)tt*32*1152;
    #pragma unroll
    for (int it=0; it<4; it++){
      int c = it*512 + tid;                 // 2304 chunks total
      int kcol = c/72, j = c - kcol*72;
      g2l16(ksrc + kcol*1152 + ((j ^ (kcol&7))<<4), kd + c*16);
    }
    if (tid < 256){
      int c = 2048 + tid;
      int kcol = c/72, j = c - kcol*72;
      g2l16(ksrc + kcol*1152 + ((j ^ (kcol&7))<<4), kd + c*16);
    }
    const char* vsrc = vd0 + (long)tt*64;   // kt0*2 bytes
    #pragma unroll
    for (int it=0; it<4; it++){
      int c = it*512 + tid;                 // 2048 chunks
      int s = c>>3, uu = (c&7) ^ (s&7);
      int d = 2*s + (uu>>2), j = uu&3;
      g2l16(vsrc + (long)d*(S_*2) + j*16, vd + c*16);
    }
  };

  for (int ph = 0; ph < 2; ++ph){
    const int qt = ph ? (31 - pr) : pr;
    const int q0 = qt * 64;

    // Q fragments: rows q0+R+c16, d = kk*32 + g*8 + 0..7
    v8bf qf[18];
    {
      const char* qgb = (const char*)Qg + (((long)z*S_ + q0 + R + c16)*576 + g*8)*2;
      #pragma unroll
      for (int kk=0;kk<18;kk++) qf[kk] = *(const v8bf*)(qgb + kk*64);
    }
    v4f acc[16];
    #pragma unroll
    for (int i=0;i<16;i++) acc[i] = (v4f){0.f,0.f,0.f,0.f};
    float m[4]  = {-1e30f,-1e30f,-1e30f,-1e30f};
    float lsum[4] = {0.f,0.f,0.f,0.f};

    const int ntile = 2*qt + 2;
    __syncthreads();                       // prior phase LDS readers done
    STAGE(0, smem + K0_OFF, smem + V0_OFF);

    for (int t = 0; t < ntile; ++t){
      asm volatile("s_waitcnt vmcnt(0)" ::: "memory");
      __syncthreads();                     // buf[t&1] staged & visible
      char* kB = smem + ((t&1) ? K1_OFF : K0_OFF);
      char* vB = smem + ((t&1) ? V1_OFF : V0_OFF);
      if (t+1 < ntile)                     // flies during compute below
        STAGE(t+1, smem + (((t+1)&1) ? K1_OFF : K0_OFF),
                    smem + (((t+1)&1) ? V1_OFF : V0_OFF));

      // ---- QK^T: 16 rows x 32 cols, K=576 ----
      v4f s0 = (v4f){0.f,0.f,0.f,0.f}, s1 = (v4f){0.f,0.f,0.f,0.f};
      #pragma unroll
      for (int kk=0;kk<18;kk++){
        int j = kk*4 + g;
        v8bf kf0 = *(const v8bf*)(kB + c16*1152      + ((j ^ (c16&7))<<4));
        v8bf kf1 = *(const v8bf*)(kB + (16+c16)*1152 + ((j ^ (c16&7))<<4));
        s0 = __builtin_amdgcn_mfma_f32_16x16x32_bf16(qf[kk], kf0, s0, 0,0,0);
        s1 = __builtin_amdgcn_mfma_f32_16x16x32_bf16(qf[kk], kf1, s1, 0,0,0);
      }
      // ---- causal mask (last two tiles of this q-tile) ----
      if (t >= ntile-2){
        int kt0 = t*32;
        #pragma unroll
        for (int r=0;r<4;r++){
          int qrow = q0 + R + g*4 + r;
          if (kt0 + c16 > qrow)      s0[r] = -1e30f;
          if (kt0 + 16 + c16 > qrow) s1[r] = -1e30f;
        }
      }
      // ---- wave-private online softmax ----
      float al[4], ps[4];
      #pragma unroll
      for (int r=0;r<4;r++){
        float v = fmaxf(s0[r], s1[r]);
        v = fmaxf(v, __shfl_xor(v, 1)); v = fmaxf(v, __shfl_xor(v, 2));
        v = fmaxf(v, __shfl_xor(v, 4)); v = fmaxf(v, __shfl_xor(v, 8));
        float mn = fmaxf(m[r], v);
        al[r] = __expf(m[r] - mn);
        m[r] = mn;
      }
      #pragma unroll
      for (int r=0;r<4;r++){
        float p0 = __expf(s0[r] - m[r]);
        float p1 = __expf(s1[r] - m[r]);
        int row = g*4 + r;
        int bse = (row>>1)*128;
        int sw  = (row>>1)&7;
        *(unsigned short*)(Pw + bse + (((((row&1)<<2)|(c16>>3)) ^ sw)<<4) + (c16&7)*2) = bfb(p0);
        *(unsigned short*)(Pw + bse + (((((row&1)<<2)|((16+c16)>>3)) ^ sw)<<4) + (c16&7)*2) = bfb(p1);
        float sv = p0 + p1;
        sv += __shfl_xor(sv, 1); sv += __shfl_xor(sv, 2);
        sv += __shfl_xor(sv, 4); sv += __shfl_xor(sv, 8);
        ps[r] = sv;
      }
      #pragma unroll
      for (int r=0;r<4;r++) lsum[r] = lsum[r]*al[r] + ps[r];
      #pragma unroll
      for (int cb=0;cb<16;cb++)
        #pragma unroll
        for (int r=0;r<4;r++) acc[cb][r] *= al[r];
      // ---- PV: 16 rows x 256 cols (d-half), K=32 ----
      {
        int prow = c16;
        int au = ((((prow&1)<<2)) | g) ^ ((prow>>1)&7);
        v8bf af = *(const v8bf*)(Pw + (prow>>1)*128 + (au<<4));
        #pragma unroll
        for (int cb=0;cb<16;cb++){
          int d = Dh + cb*16 + c16;
          int vu = ((((d&1)<<2)) | g) ^ ((d>>1)&7);
          v8bf vf = *(const v8bf*)(vB + (d>>1)*128 + (vu<<4));
          acc[cb] = __builtin_amdgcn_mfma_f32_16x16x32_bf16(af, vf, acc[cb], 0,0,0);
        }
      }
    }
    // ---- epilogue ----
    float inv[4];
    #pragma unroll
    for (int r=0;r<4;r++) inv[r] = 1.0f / lsum[r];
    #pragma unroll
    for (int cb=0;cb<16;cb++)
      #pragma unroll
      for (int r=0;r<4;r++){
        int qrow = q0 + R + g*4 + r;
        Og[((long)z*S_ + qrow)*512 + Dh + cb*16 + c16] = __float2bfloat16(acc[cb][r]*inv[r]);
      }
  }
}

// ---------------- launch ----------------------------------------------------
extern "C" void kernel_launch(void* const* d_in, const int* in_sizes, int n_in,
                              void* d_out, int out_size, void* d_ws, size_t ws_size,
                              hipStream_t stream)
{
  const float* hidden = (const float*)d_in[0];
  const float* qn_w   = (const float*)d_in[1];
  const float* qpe_w  = (const float*)d_in[2];
  const float* kva_w  = (const float*)d_in[3];
  const float* ln_w   = (const float*)d_in[4];
  const float* kb_w   = (const float*)d_in[5];
  const float* vb_w   = (const float*)d_in[6];
  const float* o_w    = (const float*)d_in[7];
  const int*   pos    = (const int*)d_in[8];
  float* out = (float*)d_out;
  char* ws = (char*)d_ws;

  float* cosT  = (float*)(ws);                 //    262144
  float* sinT  = (float*)(ws + 262144);        //    262144
  bf16*  ckvb  = (bf16*) (ws + 524288);        //  4718592  (B,S,576)
  bf16*  Qb    = (bf16*) (ws + 5242880);       // 75497472  (B*H,S,576)
  bf16*  Kb    = (bf16*) (ws + 80740352);      //  4718592  (B,S,576)
  bf16*  outl  = (bf16*) (ws + 85458944);      // 67108864  (B*H,S,512)
  bf16*  qnopeb= (bf16*) (ws + 85458944);      // 16777216  alias in outl (dead pre-attn)
  bf16*  qpeb  = (bf16*) (ws + 102236160);     //  8388608  alias in outl
  bf16*  kbT   = (bf16*) (ws + 110624768);     //  2097152  alias in outl
  bf16*  voutb = (bf16*) (ws + 152567808);     // 16777216  (B,S,2048)
  bf16*  Kd    = (bf16*) (ws + 169345024);     //  4194304  (B,512,S)  ends 173539328

  static_assert(sizeof(v8bf) == 16, "v8bf must be 16B");
  hipFuncSetAttribute((const void*)attn_mfma_kernel,
                      hipFuncAttributeMaxDynamicSharedMemorySize, SMEM_BYTES);

  cossin_kernel<<<256, 256, 0, stream>>>(pos, cosT, sinT);

  // ckv_kpe = hidden @ kv_a^T   (4096 x 576, K=2048)
  gemm_mfma_kernel<float,float,bf16><<<dim3(5,32,1),256,0,stream>>>(
      hidden,2048, 1,0,0,  kva_w,2048, 1,0,0,  ckvb,576, 1,0,0,  576,2048, 1.f);
  // q_nope = hidden @ q_nope_w^T  (4096 x 2048)
  gemm_mfma_kernel<float,float,bf16><<<dim3(16,32,1),256,0,stream>>>(
      hidden,2048, 1,0,0,  qn_w,2048, 1,0,0,  qnopeb,2048, 1,0,0,  2048,2048, 1.f);
  // q_pe_raw = hidden @ q_pe_w^T  (4096 x 1024)
  gemm_mfma_kernel<float,float,bf16><<<dim3(8,32,1),256,0,stream>>>(
      hidden,2048, 1,0,0,  qpe_w,2048, 1,0,0,  qpeb,1024, 1,0,0,  1024,2048, 1.f);

  kbT_kernel<<<dim3(8,2,16), 256, 0, stream>>>(kb_w, kbT);
  build_k_kernel<<<4096, 256, 0, stream>>>(ckvb, ln_w, cosT, sinT, Kb);
  tposeV_kernel<<<dim3(8,32,2), 256, 0, stream>>>(Kb, Kd);
  rope_q_kernel<<<8192, 256, 0, stream>>>(qpeb, cosT, sinT, Qb);

  // q_lat = q_nope @ kbT[n]^T  (per (b,n): 2048x512, K=128), *SCALE -> Q[:, :512]
  gemm_mfma_kernel<bf16,bf16,bf16><<<dim3(4,16,32),256,0,stream>>>(
      qnopeb,2048, 16,(long)S_*2048,128,  kbT,128, 16,0,65536,
      Qb,576, 1,(long)S_*576,0,  512,128, SCALE_F);

  attn_mfma_kernel<<<dim3(512), 512, SMEM_BYTES, stream>>>(Qb, Kb, Kd, outl);

  // v_out = out_lat @ v_b[n]^T  (per (b,n): 2048x128, K=512) -> (B,S,H*DV)
  gemm_mfma_kernel<bf16,float,bf16><<<dim3(1,16,32),256,0,stream>>>(
      outl,512, 1,(long)S_*512,0,  vb_w,512, 16,0,65536,
      voutb,2048, 16,(long)S_*2048,128,  128,512, 1.f);

  // out = v_out @ o_w^T  (4096 x 2048)
  gemm_mfma_kernel<bf16,float,float><<<dim3(16,32,1),256,0,stream>>>(
      voutb,2048, 1,0,0,  o_w,2048, 1,0,0,  out,2048, 1,0,0,  2048,2048, 1.f);
}